// Round 1
// baseline (886.747 us; speedup 1.0000x reference)
//
#include <hip/hip_runtime.h>

// ---------- problem constants ----------
#define T_TOK 4096
#define NROWS_MAX 10240  // 8192 routed rows + per-expert 256-alignment padding
#define MAX_TILES 40     // sum ceil(c_e/256) <= 32 + 7 = 39

typedef float  fv4  __attribute__((ext_vector_type(4)));
typedef __bf16 bv4  __attribute__((ext_vector_type(4)));
typedef __bf16 bv8  __attribute__((ext_vector_type(8)));

// ---------- workspace layout (bytes) ----------
#define CTRL_OFF     0
#define ROWTOK_OFF   4096         // int[10240]
#define ROWGATE_OFF  45056        // float[10240]
#define TOPIDX_OFF   86016        // int[8192]
#define TOPVAL_OFF   118784       // float[8192]
#define G_OFF        151552       // float[4096*256]
#define XB_OFF       4345856      // bf16[4096*2048]
#define W1T_OFF      21123072     // bf16[8*2048*2048]  ([E][H][D] = B^T)
#define W2T_OFF      88231936     // bf16[8*2048*2048]  ([E][D][H] = B^T)
#define HBUF_OFF     155340800    // bf16[10240*2048]
// total ~197 MB

struct Ctrl {
    int   counts[8];
    float psum[8];
    float entsum;
    int   ntiles;
    int   off[8];
    int   tile_e[MAX_TILES];
    int   tile_r0[MAX_TILES];
};

__device__ __forceinline__ float gelu_f(float x) {
    float x3 = x * x * x;
    return 0.5f * x * (1.0f + tanhf(0.7978845608028654f * (x + 0.044715f * x3)));
}

__device__ __forceinline__ void g2l16(const void* gptr, void* lptr) {
    __builtin_amdgcn_global_load_lds(
        (const __attribute__((address_space(1))) void*)gptr,
        (__attribute__((address_space(3))) void*)lptr, 16, 0, 0);
}

// ---------- K0a: w1/w2 fp32 -> bf16, transposed per expert ----------
__global__ __launch_bounds__(256) void transpose_cvt(
    const float* __restrict__ w1, const float* __restrict__ w2,
    __bf16* __restrict__ w1t, __bf16* __restrict__ w2t)
{
    int b    = blockIdx.x;
    int mat  = b >> 10;
    int tile = b & 1023;
    int trow = tile >> 5, tcol = tile & 31;
    const float* src = (mat < 8) ? (w1 + (size_t)mat * 4194304)
                                 : (w2 + (size_t)(mat - 8) * 4194304);
    __bf16* dst = (mat < 8) ? (w1t + (size_t)mat * 4194304)
                            : (w2t + (size_t)(mat - 8) * 4194304);
    __shared__ float tileS[64][65];
    int tid = threadIdx.x;
    int c = tid & 63, r4 = tid >> 6;
#pragma unroll
    for (int u = 0; u < 16; u++) {
        int rr = u * 4 + r4;
        tileS[rr][c] = src[(size_t)(trow * 64 + rr) * 2048 + tcol * 64 + c];
    }
    __syncthreads();
    int c2 = (tid & 31) * 2, r8 = tid >> 5;
#pragma unroll
    for (int u = 0; u < 8; u++) {
        int rr = u * 8 + r8;
        __bf16 v0 = (__bf16)tileS[c2][rr];
        __bf16 v1 = (__bf16)tileS[c2 + 1][rr];
        size_t o = (size_t)(tcol * 64 + rr) * 2048 + trow * 64 + c2;
        dst[o]     = v0;
        dst[o + 1] = v1;
    }
}

// ---------- K0b: x fp32 -> bf16 ----------
__global__ __launch_bounds__(256) void cvt_x_kernel(const float* __restrict__ x,
                                                    __bf16* __restrict__ xb)
{
    size_t idx = ((size_t)blockIdx.x * 256 + threadIdx.x) * 4;
    fv4 v = *(const fv4*)(x + idx);
    bv4 o;
#pragma unroll
    for (int u = 0; u < 4; u++) o[u] = (__bf16)v[u];
    *(bv4*)(xb + idx) = o;
}

// ---------- K1: g = gelu(x @ wg1), fp32 (top-k precision-critical) ----------
__global__ __launch_bounds__(256) void gating_gemm(const float* __restrict__ x,
                                                   const float* __restrict__ wg1,
                                                   float* __restrict__ g)
{
    __shared__ float As[16][68];
    __shared__ float Bs[16][68];
    int tid = threadIdx.x;
    int tx = tid & 15, ty = tid >> 4;
    int mb = blockIdx.x, nb = blockIdx.y;
    float acc[4][4];
#pragma unroll
    for (int u = 0; u < 4; u++)
#pragma unroll
        for (int v = 0; v < 4; v++) acc[u][v] = 0.f;

    int r  = tid >> 2, kq = tid & 3;
    int kb = tid >> 4, n4 = (tid & 15) * 4;
    const float* gx = x + (size_t)(mb * 64 + r) * 2048 + kq * 4;
    const float* gw = wg1 + nb * 64 + n4;

    for (int k0 = 0; k0 < 2048; k0 += 16) {
        fv4 av = *(const fv4*)(gx + k0);
        fv4 bv = *(const fv4*)(gw + (size_t)(k0 + kb) * 256);
        __syncthreads();
#pragma unroll
        for (int u = 0; u < 4; u++) As[kq * 4 + u][r] = av[u];
        *(fv4*)&Bs[kb][n4] = bv;
        __syncthreads();
#pragma unroll
        for (int k = 0; k < 16; k++) {
            fv4 a = *(const fv4*)&As[k][ty * 4];
            fv4 b = *(const fv4*)&Bs[k][tx * 4];
#pragma unroll
            for (int u = 0; u < 4; u++)
#pragma unroll
                for (int v = 0; v < 4; v++) acc[u][v] += a[u] * b[v];
        }
    }
#pragma unroll
    for (int u = 0; u < 4; u++) {
        int row = mb * 64 + ty * 4 + u;
#pragma unroll
        for (int v = 0; v < 4; v++)
            g[(size_t)row * 256 + nb * 64 + tx * 4 + v] = gelu_f(acc[u][v]);
    }
}

// ---------- K2: logits = g @ wg2, softmax, top-2, loss partials ----------
__global__ __launch_bounds__(256) void gate_kernel(
    const float* __restrict__ g, const float* __restrict__ wg2,
    Ctrl* __restrict__ ctrl, int* __restrict__ topidx, float* __restrict__ topval)
{
    __shared__ float wg2s[256 * 9];
    __shared__ float psum_s[8];
    __shared__ float ent_s;
    __shared__ int   cnt_s[8];
    int tid = threadIdx.x;
    for (int i = tid; i < 2048; i += 256) {
        int k = i >> 3, e = i & 7;
        wg2s[k * 9 + e] = wg2[i];
    }
    if (tid < 8) { psum_s[tid] = 0.f; cnt_s[tid] = 0; }
    if (tid == 8) ent_s = 0.f;
    __syncthreads();

    int lane = tid & 63, wv = tid >> 6;
    int t = blockIdx.x * 4 + wv;
    fv4 g4 = *(const fv4*)&g[(size_t)t * 256 + lane * 4];
    float part[8];
#pragma unroll
    for (int e = 0; e < 8; e++) part[e] = 0.f;
#pragma unroll
    for (int u = 0; u < 4; u++) {
        int k = lane * 4 + u;
        float gv = g4[u];
#pragma unroll
        for (int e = 0; e < 8; e++) part[e] += gv * wg2s[k * 9 + e];
    }
#pragma unroll
    for (int e = 0; e < 8; e++)
        for (int off = 32; off; off >>= 1) part[e] += __shfl_xor(part[e], off);

    if (lane == 0) {
        float mx = part[0];
#pragma unroll
        for (int e = 1; e < 8; e++) mx = fmaxf(mx, part[e]);
        float p[8], Z = 0.f;
#pragma unroll
        for (int e = 0; e < 8; e++) { p[e] = expf(part[e] - mx); Z += p[e]; }
        float rz = 1.f / Z;
#pragma unroll
        for (int e = 0; e < 8; e++) p[e] *= rz;
        int i0 = 0;
#pragma unroll
        for (int e = 1; e < 8; e++) if (part[e] > part[i0]) i0 = e;
        int i1 = (i0 == 0) ? 1 : 0;
#pragma unroll
        for (int e = 0; e < 8; e++)
            if (e != i0 && part[e] > part[i1]) i1 = e;
        topidx[2 * t]     = i0;
        topidx[2 * t + 1] = i1;
        topval[2 * t]     = p[i0];
        topval[2 * t + 1] = p[i1];
        float ent = 0.f;
#pragma unroll
        for (int e = 0; e < 8; e++) ent += p[e] * logf(p[e] + 1e-9f);
#pragma unroll
        for (int e = 0; e < 8; e++) atomicAdd(&psum_s[e], p[e]);
        atomicAdd(&ent_s, ent);
        atomicAdd(&cnt_s[i0], 1);
        atomicAdd(&cnt_s[i1], 1);
    }
    __syncthreads();
    if (tid < 8)                    atomicAdd(&ctrl->psum[tid], psum_s[tid]);
    else if (tid == 8)              atomicAdd(&ctrl->entsum, ent_s);
    else if (tid >= 16 && tid < 24) atomicAdd(&ctrl->counts[tid - 16], cnt_s[tid - 16]);
}

// ---------- K4: offsets + tile map (256-granular) + scatter ----------
__global__ __launch_bounds__(256) void route_kernel(
    Ctrl* __restrict__ ctrl, const int* __restrict__ topidx,
    const float* __restrict__ topval, int* __restrict__ rowtok,
    float* __restrict__ rowgate)
{
    __shared__ int cur[8];
    __shared__ int offs_s[8];
    int tid = threadIdx.x;
    if (tid == 0) {
        int off = 0, nt = 0;
        for (int e = 0; e < 8; e++) {
            offs_s[e]    = off;
            ctrl->off[e] = off;
            int c = ctrl->counts[e];
            for (int m = 0; m < c; m += 256) {
                ctrl->tile_e[nt]  = e;
                ctrl->tile_r0[nt] = off + m;
                nt++;
            }
            off += ((c + 255) >> 8) << 8;
        }
        ctrl->ntiles = nt;
    }
    if (tid < 8) cur[tid] = 0;
    __syncthreads();
    for (int t = tid; t < T_TOK; t += 256) {
#pragma unroll
        for (int k = 0; k < 2; k++) {
            int e = topidx[2 * t + k];
            int p = atomicAdd(&cur[e], 1);
            int row = offs_s[e] + p;
            rowtok[row]  = t;
            rowgate[row] = topval[2 * t + k];
        }
    }
}

// ---------- grouped MFMA GEMM: 8-phase(2 K-tiles)/counted-vmcnt template ----------
// 256x256 tile, BK=64, 8 waves (2M x 4N), double-buffered 128KB LDS.
// LDS layout per matrix: [2 buf][256 rows][8 chunks of 16B], chunk XOR-swizzled:
//   physical chunk p = logical chunk c ^ (row & 7)   (both-sides swizzle, rule #21:
//   linear global_load_lds dest + inverse-swizzled per-lane global source + swizzled ds_read)
// Schedule per K-tile (4 phases), stage order of NEXT K-tile = first-need order [A0,B0,B1,A1]:
//   P1: ds{A0,B0} | stage A0' | vmcnt(4) bar | mfma C(0,0) | bar
//   P2: ds{B1}    | stage B0' | vmcnt(4) bar | mfma C(0,1) | bar
//   P3: ds{A1}    | stage B1' | vmcnt(4) bar | mfma C(1,1) | bar
//   P4:           | stage A1' | vmcnt(4) bar | mfma C(1,0) | bar
// vmcnt(4) keeps 2 half-tiles (4 loads/thread) in flight across barriers; the wait at
// phase g guarantees halves <= g+2 landed, which is exactly what phase g+1's ds_reads need.
#define WAIT_VM4 0x0F74   // vmcnt(4), lgkm/exp don't-care
#define WAIT_VM0 0x0F70   // vmcnt(0)

__device__ __forceinline__ void ld_af8(const __bf16* sm, int off, int l15, int pb8,
                                       bv8 f[4][2]) {
#pragma unroll
    for (int mi = 0; mi < 4; mi++)
#pragma unroll
        for (int ks = 0; ks < 2; ks++)
            f[mi][ks] = *(const bv8*)&sm[off + mi * 1024 + l15 * 64 + (pb8 ^ (ks << 5))];
}

__device__ __forceinline__ void ld_bf4(const __bf16* sm, int off, int l15, int pb8,
                                       bv8 f[2][2]) {
#pragma unroll
    for (int ni = 0; ni < 2; ni++)
#pragma unroll
        for (int ks = 0; ks < 2; ks++)
            f[ni][ks] = *(const bv8*)&sm[off + ni * 1024 + l15 * 64 + (pb8 ^ (ks << 5))];
}

__device__ __forceinline__ void mm16(fv4 ac[4][2], const bv8 a[4][2], const bv8 b[2][2]) {
    __builtin_amdgcn_s_setprio(1);
#pragma unroll
    for (int mi = 0; mi < 4; mi++)
#pragma unroll
        for (int ni = 0; ni < 2; ni++)
#pragma unroll
            for (int ks = 0; ks < 2; ks++)
                ac[mi][ni] = __builtin_amdgcn_mfma_f32_16x16x32_bf16(
                    a[mi][ks], b[ni][ks], ac[mi][ni], 0, 0, 0);
    __builtin_amdgcn_s_setprio(0);
}

#define VM4 __builtin_amdgcn_s_waitcnt(WAIT_VM4)
#define VM0 __builtin_amdgcn_s_waitcnt(WAIT_VM0)
#define BAR __builtin_amdgcn_s_barrier()

// One K-tile (BK=64): BUF is a literal 0/1; KN = (kt+1)*64 element k-offset of staged tile.
#define KT_STEP(BUF, KN)                                                          \
    {                                                                             \
        const int Ab = (BUF) * 16384, Bb = 32768 + (BUF) * 16384;                 \
        const int An = ((BUF) ^ 1) * 16384, Bn = 32768 + (((BUF) ^ 1) * 16384);   \
        bv8 aF[4][2], bF0[2][2], bF1[2][2];                                       \
        ld_af8(smem, Ab + A0W, l15, pb8, aF);                                     \
        ld_bf4(smem, Bb + B0W, l15, pb8, bF0);                                    \
        g2l16(pa00 + (KN), smem + An + stbase);                                   \
        g2l16(pa01 + (KN), smem + An + 4096 + stbase);                            \
        VM4; BAR; mm16(acc[0][0], aF, bF0); BAR;                                  \
        ld_bf4(smem, Bb + B1W, l15, pb8, bF1);                                    \
        g2l16(pb00 + (KN), smem + Bn + stbase);                                   \
        g2l16(pb01 + (KN), smem + Bn + 4096 + stbase);                            \
        VM4; BAR; mm16(acc[0][1], aF, bF1); BAR;                                  \
        ld_af8(smem, Ab + A1W, l15, pb8, aF);                                     \
        g2l16(pb10 + (KN), smem + Bn + 8192 + stbase);                            \
        g2l16(pb11 + (KN), smem + Bn + 8192 + 4096 + stbase);                     \
        VM4; BAR; mm16(acc[1][1], aF, bF1); BAR;                                  \
        g2l16(pa10 + (KN), smem + An + 8192 + stbase);                            \
        g2l16(pa11 + (KN), smem + An + 8192 + 4096 + stbase);                     \
        VM4; BAR; mm16(acc[1][0], aF, bF0); BAR;                                  \
    }

template <bool IS_FFN1>
__global__ __launch_bounds__(512, 2) void gemm_grouped(
    const __bf16* __restrict__ A,
    const __bf16* __restrict__ Bt,   // [E][N=2048][K=2048] (B^T)
    const Ctrl* __restrict__ ctrl,
    const int* __restrict__ rowtok,
    const float* __restrict__ rowgate,
    __bf16* __restrict__ hbuf,
    float* __restrict__ y)
{
    __shared__ __bf16 smem[65536];   // A: [2][256][64] @0, B: [2][256][64] @32768 (128 KB)

    const int tid  = threadIdx.x;
    const int lane = tid & 63, w = tid >> 6;
    const int wm = w >> 2, wn = w & 3;                 // 2 x 4 wave grid
    const int l15 = lane & 15;
    const int pb8 = (((lane >> 4) ^ (lane & 7)) << 3); // swizzled chunk*8 (ks=0)
    const int rowL = (lane >> 4) * 4;                  // C/D row sub-offset

    // fragment row-base offsets (elements) within a buffer
    const int A0W = wm * 4096;                         // qa=0 rows wm*64
    const int A1W = 8192 + wm * 4096;                  // qa=1
    const int B0W = wn * 2048;                         // qb=0 cols wn*32
    const int B1W = 8192 + wn * 2048;                  // qb=1

    // staging thread constants: thread t covers row (t>>3) of a 64-row slab,
    // physical chunk t&7; inverse-swizzled source chunk:
    const int srow   = tid >> 3;
    const int schunk = (tid & 7) ^ ((tid >> 3) & 7);
    const int stbase = w * 512;                        // + lane*16B added by HW

    int ntiles = ctrl->ntiles;
    int x = blockIdx.x & 7, s = blockIdx.x >> 3;       // xcd, cu-slot

    int items[2]; int ni = 0;
    {
        int i0 = x * 32 + s;
        int tl = ((i0 >> 5) << 2) | (i0 & 3);
        if (tl < ntiles) items[ni++] = i0;
    }
    if (s < 8) {
        int i1 = 256 + x * 8 + s;
        int tl = ((i1 >> 5) << 2) | (i1 & 3);
        if (tl < ntiles) items[ni++] = i1;
    }

    for (int it = 0; it < ni; it++) {
        int item = items[it];
        int idx  = item & 31;
        int tl   = ((item >> 5) << 2) | (idx & 3);
        int nb   = (idx >> 2) & 7;
        int e    = ctrl->tile_e[tl];
        int r0   = ctrl->tile_r0[tl];

        // per-thread staging source pointers (k=0); rows fixed across K
        size_t ar00, ar01, ar10, ar11;
        if constexpr (IS_FFN1) {
            ar00 = (size_t)rowtok[r0 + srow];
            ar01 = (size_t)rowtok[r0 + 64 + srow];
            ar10 = (size_t)rowtok[r0 + 128 + srow];
            ar11 = (size_t)rowtok[r0 + 192 + srow];
        } else {
            ar00 = (size_t)(r0 + srow);
            ar01 = (size_t)(r0 + 64 + srow);
            ar10 = (size_t)(r0 + 128 + srow);
            ar11 = (size_t)(r0 + 192 + srow);
        }
        const __bf16* pa00 = A + ar00 * 2048 + schunk * 8;
        const __bf16* pa01 = A + ar01 * 2048 + schunk * 8;
        const __bf16* pa10 = A + ar10 * 2048 + schunk * 8;
        const __bf16* pa11 = A + ar11 * 2048 + schunk * 8;
        size_t bb = (size_t)e * 2048 + nb * 256;
        const __bf16* pb00 = Bt + (bb + srow) * 2048 + schunk * 8;
        const __bf16* pb01 = Bt + (bb + 64 + srow) * 2048 + schunk * 8;
        const __bf16* pb10 = Bt + (bb + 128 + srow) * 2048 + schunk * 8;
        const __bf16* pb11 = Bt + (bb + 192 + srow) * 2048 + schunk * 8;

        fv4 acc[2][2][4][2];
#pragma unroll
        for (int qa = 0; qa < 2; qa++)
#pragma unroll
            for (int qb = 0; qb < 2; qb++)
#pragma unroll
                for (int mi = 0; mi < 4; mi++)
#pragma unroll
                    for (int nj = 0; nj < 2; nj++) acc[qa][qb][mi][nj] = (fv4)0.0f;

        // prologue: all waves done reading LDS from previous item, then stage
        // K-tile 0 into buf0 in first-need order [A0, B0, B1, A1]
        BAR;
        g2l16(pa00, smem + stbase);
        g2l16(pa01, smem + 4096 + stbase);
        g2l16(pb00, smem + 32768 + stbase);
        g2l16(pb01, smem + 32768 + 4096 + stbase);
        g2l16(pb10, smem + 32768 + 8192 + stbase);
        g2l16(pb11, smem + 32768 + 8192 + 4096 + stbase);
        g2l16(pa10, smem + 8192 + stbase);
        g2l16(pa11, smem + 8192 + 4096 + stbase);
        VM4;   // A0,B0 of Kt0 landed
        BAR;

        // main loop: 32 K-tiles; unroll 2 K-tiles/iter so buffer index is literal
#pragma unroll 1
        for (int k2 = 0; k2 < 15; k2++) {
            int kn = ((k2 * 2) + 1) << 6;
            KT_STEP(0, kn);
            KT_STEP(1, kn + 64);
        }
        KT_STEP(0, 31 << 6);   // kt=30 (buf0), stages Kt31 into buf1

        // kt=31 drain (buf1): only place with vmcnt(0); no staging, no more barriers
        {
            bv8 aF[4][2], bF0[2][2], bF1[2][2];
            ld_af8(smem, 16384 + A0W, l15, pb8, aF);
            ld_bf4(smem, 49152 + B0W, l15, pb8, bF0);
            VM0;
            BAR;
            mm16(acc[0][0], aF, bF0);
            ld_bf4(smem, 49152 + B1W, l15, pb8, bF1);
            mm16(acc[0][1], aF, bF1);
            ld_af8(smem, 16384 + A1W, l15, pb8, aF);
            mm16(acc[1][1], aF, bF1);
            mm16(acc[1][0], aF, bF0);
        }

        // epilogue: C/D layout col=lane&15, row=(lane>>4)*4+reg
#pragma unroll
        for (int qa = 0; qa < 2; qa++) {
#pragma unroll
            for (int mi = 0; mi < 4; mi++) {
                int rbase = r0 + qa * 128 + wm * 64 + mi * 16 + rowL;
#pragma unroll
                for (int rr = 0; rr < 4; rr++) {
                    int rg = rbase + rr;
                    if constexpr (IS_FFN1) {
                        float gate = rowgate[rg];
                        size_t ho = (size_t)rg * 2048;
#pragma unroll
                        for (int qb = 0; qb < 2; qb++)
#pragma unroll
                            for (int nj = 0; nj < 2; nj++) {
                                int col = nb * 256 + qb * 128 + wn * 32 + nj * 16 + l15;
                                hbuf[ho + col] =
                                    (__bf16)(gelu_f(acc[qa][qb][mi][nj][rr]) * gate);
                            }
                    } else {
                        size_t yo = (size_t)rowtok[rg] * 2048;
#pragma unroll
                        for (int qb = 0; qb < 2; qb++)
#pragma unroll
                            for (int nj = 0; nj < 2; nj++) {
                                int col = nb * 256 + qb * 128 + wn * 32 + nj * 16 + l15;
                                atomicAdd(&y[yo + col], acc[qa][qb][mi][nj][rr]);
                            }
                    }
                }
            }
        }
    }
}

// ---------- K5: final loss scalar ----------
__global__ __launch_bounds__(64) void loss_kernel(const Ctrl* __restrict__ ctrl,
                                                  float* __restrict__ out)
{
    if (threadIdx.x == 0) {
        float a = 0.f;
#pragma unroll
        for (int e = 0; e < 8; e++) {
            float pm = ctrl->psum[e] * (1.0f / 4096.0f);
            a += pm * logf(pm + 1e-9f);
        }
        out[0] = a - ctrl->entsum * (1.0f / 4096.0f);
    }
}

extern "C" void kernel_launch(void* const* d_in, const int* in_sizes, int n_in,
                              void* d_out, int out_size, void* d_ws, size_t ws_size,
                              hipStream_t stream)
{
    const float* x   = (const float*)d_in[0];
    const float* wg1 = (const float*)d_in[1];
    const float* wg2 = (const float*)d_in[2];
    const float* w1  = (const float*)d_in[3];
    const float* w2  = (const float*)d_in[4];
    float* out = (float*)d_out;

    char* ws = (char*)d_ws;
    Ctrl*   ctrl    = (Ctrl*)(ws + CTRL_OFF);
    int*    rowtok  = (int*)(ws + ROWTOK_OFF);
    float*  rowgate = (float*)(ws + ROWGATE_OFF);
    int*    topidx  = (int*)(ws + TOPIDX_OFF);
    float*  topval  = (float*)(ws + TOPVAL_OFF);
    float*  g       = (float*)(ws + G_OFF);
    __bf16* xb      = (__bf16*)(ws + XB_OFF);
    __bf16* w1t     = (__bf16*)(ws + W1T_OFF);
    __bf16* w2t     = (__bf16*)(ws + W2T_OFF);
    __bf16* hbuf    = (__bf16*)(ws + HBUF_OFF);

    hipMemsetAsync(ws + CTRL_OFF, 0, 4096, stream);
    hipMemsetAsync(ws + ROWTOK_OFF, 0, 81920, stream);   // rowtok + rowgate
    hipMemsetAsync(d_out, 0, (size_t)out_size * sizeof(float), stream);

    transpose_cvt<<<16384, 256, 0, stream>>>(w1, w2, w1t, w2t);
    cvt_x_kernel<<<8192, 256, 0, stream>>>(x, xb);
    gating_gemm<<<dim3(64, 4), 256, 0, stream>>>(x, wg1, g);
    gate_kernel<<<1024, 256, 0, stream>>>(g, wg2, ctrl, topidx, topval);
    route_kernel<<<1, 256, 0, stream>>>(ctrl, topidx, topval, rowtok, rowgate);
    gemm_grouped<true><<<256, 512, 0, stream>>>(xb, w1t, ctrl, rowtok, rowgate, hbuf, nullptr);
    gemm_grouped<false><<<256, 512, 0, stream>>>(hbuf, w2t, ctrl, rowtok, rowgate, nullptr, out);
    loss_kernel<<<1, 64, 0, stream>>>(ctrl, out + 8388608);
}

// Round 2
// 832.270 us; speedup vs baseline: 1.0655x; 1.0655x over previous
//
#include <hip/hip_runtime.h>

// ---------- problem constants ----------
#define T_TOK 4096
#define NROWS_MAX 10240  // 8192 routed rows + per-expert 128-alignment padding (<= 9208)
#define MAX_TILES 72     // sum ceil(c_e/128) <= 64 + 7 = 71

typedef float  fv4  __attribute__((ext_vector_type(4)));
typedef __bf16 bv4  __attribute__((ext_vector_type(4)));
typedef __bf16 bv8  __attribute__((ext_vector_type(8)));

// ---------- workspace layout (bytes) ----------
#define CTRL_OFF     0
#define ROWTOK_OFF   4096         // int[10240]
#define ROWGATE_OFF  45056        // float[10240]
#define TOPIDX_OFF   86016        // int[8192]
#define TOPVAL_OFF   118784       // float[8192]
#define G_OFF        151552       // float[4096*256]
#define XB_OFF       4345856      // bf16[4096*2048]
#define W1T_OFF      21123072     // bf16[8*2048*2048]  ([E][H][D] = B^T)
#define W2T_OFF      88231936     // bf16[8*2048*2048]  ([E][D][H] = B^T)
#define HBUF_OFF     155340800    // bf16[10240*2048]
// total ~197 MB

struct Ctrl {
    int   counts[8];
    float psum[8];
    float entsum;
    int   ntiles;
    int   off[8];
    int   tile_e[MAX_TILES];
    int   tile_r0[MAX_TILES];
};

__device__ __forceinline__ float gelu_f(float x) {
    float x3 = x * x * x;
    return 0.5f * x * (1.0f + tanhf(0.7978845608028654f * (x + 0.044715f * x3)));
}

__device__ __forceinline__ void g2l16(const void* gptr, void* lptr) {
    __builtin_amdgcn_global_load_lds(
        (const __attribute__((address_space(1))) void*)gptr,
        (__attribute__((address_space(3))) void*)lptr, 16, 0, 0);
}

// ---------- K0a: w1/w2 fp32 -> bf16, transposed per expert ----------
__global__ __launch_bounds__(256) void transpose_cvt(
    const float* __restrict__ w1, const float* __restrict__ w2,
    __bf16* __restrict__ w1t, __bf16* __restrict__ w2t)
{
    int b    = blockIdx.x;
    int mat  = b >> 10;
    int tile = b & 1023;
    int trow = tile >> 5, tcol = tile & 31;
    const float* src = (mat < 8) ? (w1 + (size_t)mat * 4194304)
                                 : (w2 + (size_t)(mat - 8) * 4194304);
    __bf16* dst = (mat < 8) ? (w1t + (size_t)mat * 4194304)
                            : (w2t + (size_t)(mat - 8) * 4194304);
    __shared__ float tileS[64][65];
    int tid = threadIdx.x;
    int c = tid & 63, r4 = tid >> 6;
#pragma unroll
    for (int u = 0; u < 16; u++) {
        int rr = u * 4 + r4;
        tileS[rr][c] = src[(size_t)(trow * 64 + rr) * 2048 + tcol * 64 + c];
    }
    __syncthreads();
    int c2 = (tid & 31) * 2, r8 = tid >> 5;
#pragma unroll
    for (int u = 0; u < 8; u++) {
        int rr = u * 8 + r8;
        __bf16 v0 = (__bf16)tileS[c2][rr];
        __bf16 v1 = (__bf16)tileS[c2 + 1][rr];
        size_t o = (size_t)(tcol * 64 + rr) * 2048 + trow * 64 + c2;
        dst[o]     = v0;
        dst[o + 1] = v1;
    }
}

// ---------- K0b: x fp32 -> bf16 ----------
__global__ __launch_bounds__(256) void cvt_x_kernel(const float* __restrict__ x,
                                                    __bf16* __restrict__ xb)
{
    size_t idx = ((size_t)blockIdx.x * 256 + threadIdx.x) * 4;
    fv4 v = *(const fv4*)(x + idx);
    bv4 o;
#pragma unroll
    for (int u = 0; u < 4; u++) o[u] = (__bf16)v[u];
    *(bv4*)(xb + idx) = o;
}

// ---------- K1: g = gelu(x @ wg1), fp32 (top-k precision-critical) ----------
__global__ __launch_bounds__(256) void gating_gemm(const float* __restrict__ x,
                                                   const float* __restrict__ wg1,
                                                   float* __restrict__ g)
{
    __shared__ float As[16][68];
    __shared__ float Bs[16][68];
    int tid = threadIdx.x;
    int tx = tid & 15, ty = tid >> 4;
    int mb = blockIdx.x, nb = blockIdx.y;
    float acc[4][4];
#pragma unroll
    for (int u = 0; u < 4; u++)
#pragma unroll
        for (int v = 0; v < 4; v++) acc[u][v] = 0.f;

    int r  = tid >> 2, kq = tid & 3;
    int kb = tid >> 4, n4 = (tid & 15) * 4;
    const float* gx = x + (size_t)(mb * 64 + r) * 2048 + kq * 4;
    const float* gw = wg1 + nb * 64 + n4;

    for (int k0 = 0; k0 < 2048; k0 += 16) {
        fv4 av = *(const fv4*)(gx + k0);
        fv4 bv = *(const fv4*)(gw + (size_t)(k0 + kb) * 256);
        __syncthreads();
#pragma unroll
        for (int u = 0; u < 4; u++) As[kq * 4 + u][r] = av[u];
        *(fv4*)&Bs[kb][n4] = bv;
        __syncthreads();
#pragma unroll
        for (int k = 0; k < 16; k++) {
            fv4 a = *(const fv4*)&As[k][ty * 4];
            fv4 b = *(const fv4*)&Bs[k][tx * 4];
#pragma unroll
            for (int u = 0; u < 4; u++)
#pragma unroll
                for (int v = 0; v < 4; v++) acc[u][v] += a[u] * b[v];
        }
    }
#pragma unroll
    for (int u = 0; u < 4; u++) {
        int row = mb * 64 + ty * 4 + u;
#pragma unroll
        for (int v = 0; v < 4; v++)
            g[(size_t)row * 256 + nb * 64 + tx * 4 + v] = gelu_f(acc[u][v]);
    }
}

// ---------- K2: logits = g @ wg2, softmax, top-2, loss partials ----------
__global__ __launch_bounds__(256) void gate_kernel(
    const float* __restrict__ g, const float* __restrict__ wg2,
    Ctrl* __restrict__ ctrl, int* __restrict__ topidx, float* __restrict__ topval)
{
    __shared__ float wg2s[256 * 9];
    __shared__ float psum_s[8];
    __shared__ float ent_s;
    __shared__ int   cnt_s[8];
    int tid = threadIdx.x;
    for (int i = tid; i < 2048; i += 256) {
        int k = i >> 3, e = i & 7;
        wg2s[k * 9 + e] = wg2[i];
    }
    if (tid < 8) { psum_s[tid] = 0.f; cnt_s[tid] = 0; }
    if (tid == 8) ent_s = 0.f;
    __syncthreads();

    int lane = tid & 63, wv = tid >> 6;
    int t = blockIdx.x * 4 + wv;
    fv4 g4 = *(const fv4*)&g[(size_t)t * 256 + lane * 4];
    float part[8];
#pragma unroll
    for (int e = 0; e < 8; e++) part[e] = 0.f;
#pragma unroll
    for (int u = 0; u < 4; u++) {
        int k = lane * 4 + u;
        float gv = g4[u];
#pragma unroll
        for (int e = 0; e < 8; e++) part[e] += gv * wg2s[k * 9 + e];
    }
#pragma unroll
    for (int e = 0; e < 8; e++)
        for (int off = 32; off; off >>= 1) part[e] += __shfl_xor(part[e], off);

    if (lane == 0) {
        float mx = part[0];
#pragma unroll
        for (int e = 1; e < 8; e++) mx = fmaxf(mx, part[e]);
        float p[8], Z = 0.f;
#pragma unroll
        for (int e = 0; e < 8; e++) { p[e] = expf(part[e] - mx); Z += p[e]; }
        float rz = 1.f / Z;
#pragma unroll
        for (int e = 0; e < 8; e++) p[e] *= rz;
        int i0 = 0;
#pragma unroll
        for (int e = 1; e < 8; e++) if (part[e] > part[i0]) i0 = e;
        int i1 = (i0 == 0) ? 1 : 0;
#pragma unroll
        for (int e = 0; e < 8; e++)
            if (e != i0 && part[e] > part[i1]) i1 = e;
        topidx[2 * t]     = i0;
        topidx[2 * t + 1] = i1;
        topval[2 * t]     = p[i0];
        topval[2 * t + 1] = p[i1];
        float ent = 0.f;
#pragma unroll
        for (int e = 0; e < 8; e++) ent += p[e] * logf(p[e] + 1e-9f);
#pragma unroll
        for (int e = 0; e < 8; e++) atomicAdd(&psum_s[e], p[e]);
        atomicAdd(&ent_s, ent);
        atomicAdd(&cnt_s[i0], 1);
        atomicAdd(&cnt_s[i1], 1);
    }
    __syncthreads();
    if (tid < 8)                    atomicAdd(&ctrl->psum[tid], psum_s[tid]);
    else if (tid == 8)              atomicAdd(&ctrl->entsum, ent_s);
    else if (tid >= 16 && tid < 24) atomicAdd(&ctrl->counts[tid - 16], cnt_s[tid - 16]);
}

// ---------- K4: offsets + tile map (128-granular) + scatter ----------
__global__ __launch_bounds__(256) void route_kernel(
    Ctrl* __restrict__ ctrl, const int* __restrict__ topidx,
    const float* __restrict__ topval, int* __restrict__ rowtok,
    float* __restrict__ rowgate)
{
    __shared__ int cur[8];
    __shared__ int offs_s[8];
    int tid = threadIdx.x;
    if (tid == 0) {
        int off = 0, nt = 0;
        for (int e = 0; e < 8; e++) {
            offs_s[e]    = off;
            ctrl->off[e] = off;
            int c = ctrl->counts[e];
            for (int m = 0; m < c; m += 128) {
                ctrl->tile_e[nt]  = e;
                ctrl->tile_r0[nt] = off + m;
                nt++;
            }
            off += ((c + 127) >> 7) << 7;
        }
        ctrl->ntiles = nt;
    }
    if (tid < 8) cur[tid] = 0;
    __syncthreads();
    for (int t = tid; t < T_TOK; t += 256) {
#pragma unroll
        for (int k = 0; k < 2; k++) {
            int e = topidx[2 * t + k];
            int p = atomicAdd(&cur[e], 1);
            int row = offs_s[e] + p;
            rowtok[row]  = t;
            rowgate[row] = topval[2 * t + k];
        }
    }
}

// ---------- grouped MFMA GEMM: m97-proven structure ----------
// 128x128 tile, BK=32, 4 waves (2x2), single-buffered 16KB LDS, plain
// __syncthreads() double-barrier K-loop. 3 blocks/CU (__launch_bounds__(256,3))
// provide the TLP that hides the barrier vmcnt drain (m97: 874-912 TF; explicit
// pipelining on this structure is neutral, m99-m141). Persistent grid of 768
// blocks (3 x 256 CUs), grid-stride over ntiles*16 items, XCD-chunked swizzle.
#define NBLK 768

template <bool IS_FFN1>
__global__ __launch_bounds__(256, 3) void gemm_grouped(
    const __bf16* __restrict__ A,
    const __bf16* __restrict__ Bt,   // [E][N=2048][K=2048] (B^T)
    const Ctrl* __restrict__ ctrl,
    const int* __restrict__ rowtok,
    const float* __restrict__ rowgate,
    __bf16* __restrict__ hbuf,
    float* __restrict__ y)
{
    __shared__ __bf16 As[128 * 32];  // 8 KB
    __shared__ __bf16 Bs[128 * 32];  // 8 KB

    const int tid  = threadIdx.x;
    const int lane = tid & 63, w = tid >> 6;
    const int wm = w >> 1, wn = w & 1;        // 2x2 wave grid, 64x64 per wave
    const int l15 = lane & 15;
    const int kq8 = (lane >> 4) * 8;          // k-slice element offset in frag row
    const int stb = w * 512;                  // wave-uniform LDS dest (elements)
    const int srow = tid >> 2;                // staging source row (0..63)
    const int sk8  = (tid & 3) * 8;           // staging k-chunk (elements)

    int ntiles = ctrl->ntiles;
    int nitems = ntiles << 4;                 // x 16 col panels (nb)
    int sw = (blockIdx.x & 7) * (NBLK / 8) + (blockIdx.x >> 3);  // XCD-chunked

    for (int item = sw; item < nitems; item += NBLK) {
        int tl = item >> 4, nb = item & 15;
        int e  = ctrl->tile_e[tl];
        int r0 = ctrl->tile_r0[tl];

        // staging source pointers (k=0)
        int rA0, rA1;
        if constexpr (IS_FFN1) {
            rA0 = rowtok[r0 + srow];
            rA1 = rowtok[r0 + 64 + srow];
        } else {
            rA0 = r0 + srow;
            rA1 = rA0 + 64;
        }
        const __bf16* pa0 = A + (size_t)rA0 * 2048 + sk8;
        const __bf16* pa1 = A + (size_t)rA1 * 2048 + sk8;
        const __bf16* pb0 = Bt + ((size_t)e * 2048 + nb * 128 + srow) * 2048 + sk8;
        const __bf16* pb1 = pb0 + (size_t)64 * 2048;

        fv4 acc[4][4];
#pragma unroll
        for (int i = 0; i < 4; i++)
#pragma unroll
            for (int j = 0; j < 4; j++) acc[i][j] = (fv4)0.0f;

        for (int k = 0; k < 2048; k += 32) {
            __syncthreads();                    // prior step's reads complete
            g2l16(pa0 + k, As + stb);           // rows 0..63
            g2l16(pa1 + k, As + 2048 + stb);    // rows 64..127
            g2l16(pb0 + k, Bs + stb);
            g2l16(pb1 + k, Bs + 2048 + stb);
            __syncthreads();                    // compiler drains vmcnt before barrier

            bv8 aF[4], bF[4];
#pragma unroll
            for (int i = 0; i < 4; i++)
                aF[i] = *(const bv8*)&As[(wm * 64 + i * 16 + l15) * 32 + kq8];
#pragma unroll
            for (int j = 0; j < 4; j++)
                bF[j] = *(const bv8*)&Bs[(wn * 64 + j * 16 + l15) * 32 + kq8];
#pragma unroll
            for (int i = 0; i < 4; i++)
#pragma unroll
                for (int j = 0; j < 4; j++)
                    acc[i][j] = __builtin_amdgcn_mfma_f32_16x16x32_bf16(
                        aF[i], bF[j], acc[i][j], 0, 0, 0);
        }

        // epilogue: C/D layout col=lane&15, row=(lane>>4)*4+reg
        int colb = nb * 128 + wn * 64 + l15;
        int rb   = r0 + wm * 64 + (lane >> 4) * 4;
#pragma unroll
        for (int i = 0; i < 4; i++) {
#pragma unroll
            for (int rr = 0; rr < 4; rr++) {
                int rg = rb + i * 16 + rr;
                if constexpr (IS_FFN1) {
                    float gate = rowgate[rg];
                    size_t ho = (size_t)rg * 2048;
#pragma unroll
                    for (int j = 0; j < 4; j++)
                        hbuf[ho + colb + j * 16] = (__bf16)(gelu_f(acc[i][j][rr]) * gate);
                } else {
                    size_t yo = (size_t)rowtok[rg] * 2048;
#pragma unroll
                    for (int j = 0; j < 4; j++)
                        atomicAdd(&y[yo + colb + j * 16], acc[i][j][rr]);
                }
            }
        }
    }
}

// ---------- K5: final loss scalar ----------
__global__ __launch_bounds__(64) void loss_kernel(const Ctrl* __restrict__ ctrl,
                                                  float* __restrict__ out)
{
    if (threadIdx.x == 0) {
        float a = 0.f;
#pragma unroll
        for (int e = 0; e < 8; e++) {
            float pm = ctrl->psum[e] * (1.0f / 4096.0f);
            a += pm * logf(pm + 1e-9f);
        }
        out[0] = a - ctrl->entsum * (1.0f / 4096.0f);
    }
}

extern "C" void kernel_launch(void* const* d_in, const int* in_sizes, int n_in,
                              void* d_out, int out_size, void* d_ws, size_t ws_size,
                              hipStream_t stream)
{
    const float* x   = (const float*)d_in[0];
    const float* wg1 = (const float*)d_in[1];
    const float* wg2 = (const float*)d_in[2];
    const float* w1  = (const float*)d_in[3];
    const float* w2  = (const float*)d_in[4];
    float* out = (float*)d_out;

    char* ws = (char*)d_ws;
    Ctrl*   ctrl    = (Ctrl*)(ws + CTRL_OFF);
    int*    rowtok  = (int*)(ws + ROWTOK_OFF);
    float*  rowgate = (float*)(ws + ROWGATE_OFF);
    int*    topidx  = (int*)(ws + TOPIDX_OFF);
    float*  topval  = (float*)(ws + TOPVAL_OFF);
    float*  g       = (float*)(ws + G_OFF);
    __bf16* xb      = (__bf16*)(ws + XB_OFF);
    __bf16* w1t     = (__bf16*)(ws + W1T_OFF);
    __bf16* w2t     = (__bf16*)(ws + W2T_OFF);
    __bf16* hbuf    = (__bf16*)(ws + HBUF_OFF);

    hipMemsetAsync(ws + CTRL_OFF, 0, 4096, stream);
    hipMemsetAsync(ws + ROWTOK_OFF, 0, 81920, stream);   // rowtok + rowgate
    hipMemsetAsync(d_out, 0, (size_t)out_size * sizeof(float), stream);

    transpose_cvt<<<16384, 256, 0, stream>>>(w1, w2, w1t, w2t);
    cvt_x_kernel<<<8192, 256, 0, stream>>>(x, xb);
    gating_gemm<<<dim3(64, 4), 256, 0, stream>>>(x, wg1, g);
    gate_kernel<<<1024, 256, 0, stream>>>(g, wg2, ctrl, topidx, topval);
    route_kernel<<<1, 256, 0, stream>>>(ctrl, topidx, topval, rowtok, rowgate);
    gemm_grouped<true><<<NBLK, 256, 0, stream>>>(xb, w1t, ctrl, rowtok, rowgate, hbuf, nullptr);
    gemm_grouped<false><<<NBLK, 256, 0, stream>>>(hbuf, w2t, ctrl, rowtok, rowgate, nullptr, out);
    loss_kernel<<<1, 64, 0, stream>>>(ctrl, out + 8388608);
}

// Round 3
// 815.027 us; speedup vs baseline: 1.0880x; 1.0212x over previous
//
#include <hip/hip_runtime.h>

// ---------- problem constants ----------
#define T_TOK 4096
#define NROWS_MAX 10240  // 8192 routed rows + per-expert 128-alignment padding (<= 9208)
#define MAX_TILES 72     // sum ceil(c_e/128) <= 64 + 7 = 71

typedef float  fv4  __attribute__((ext_vector_type(4)));
typedef __bf16 bv4  __attribute__((ext_vector_type(4)));
typedef __bf16 bv8  __attribute__((ext_vector_type(8)));

// ---------- workspace layout (bytes) ----------
#define CTRL_OFF     0
#define ROWTOK_OFF   4096         // int[10240]
#define ROWGATE_OFF  45056        // float[10240]
#define TOPIDX_OFF   86016        // int[8192]
#define TOPVAL_OFF   118784       // float[8192]
#define G_OFF        151552       // float[4096*256]
#define XB_OFF       4345856      // bf16[4096*2048]
#define W1T_OFF      21123072     // bf16[8*2048*2048]  ([E][H][D] = B^T)
#define W2T_OFF      88231936     // bf16[8*2048*2048]  ([E][D][H] = B^T)
#define HBUF_OFF     155340800    // bf16[10240*2048]
// total ~197 MB

struct Ctrl {
    int   counts[8];
    float psum[8];
    float entsum;
    int   ntiles;
    int   off[8];
    int   tile_e[MAX_TILES];
    int   tile_r0[MAX_TILES];
};

__device__ __forceinline__ float gelu_f(float x) {
    float x3 = x * x * x;
    return 0.5f * x * (1.0f + tanhf(0.7978845608028654f * (x + 0.044715f * x3)));
}

__device__ __forceinline__ void g2l16(const void* gptr, void* lptr) {
    __builtin_amdgcn_global_load_lds(
        (const __attribute__((address_space(1))) void*)gptr,
        (__attribute__((address_space(3))) void*)lptr, 16, 0, 0);
}

// ---------- K0a: w1/w2 fp32 -> bf16, transposed per expert ----------
__global__ __launch_bounds__(256) void transpose_cvt(
    const float* __restrict__ w1, const float* __restrict__ w2,
    __bf16* __restrict__ w1t, __bf16* __restrict__ w2t)
{
    int b    = blockIdx.x;
    int mat  = b >> 10;
    int tile = b & 1023;
    int trow = tile >> 5, tcol = tile & 31;
    const float* src = (mat < 8) ? (w1 + (size_t)mat * 4194304)
                                 : (w2 + (size_t)(mat - 8) * 4194304);
    __bf16* dst = (mat < 8) ? (w1t + (size_t)mat * 4194304)
                            : (w2t + (size_t)(mat - 8) * 4194304);
    __shared__ float tileS[64][65];
    int tid = threadIdx.x;
    int c = tid & 63, r4 = tid >> 6;
#pragma unroll
    for (int u = 0; u < 16; u++) {
        int rr = u * 4 + r4;
        tileS[rr][c] = src[(size_t)(trow * 64 + rr) * 2048 + tcol * 64 + c];
    }
    __syncthreads();
    int c2 = (tid & 31) * 2, r8 = tid >> 5;
#pragma unroll
    for (int u = 0; u < 8; u++) {
        int rr = u * 8 + r8;
        __bf16 v0 = (__bf16)tileS[c2][rr];
        __bf16 v1 = (__bf16)tileS[c2 + 1][rr];
        size_t o = (size_t)(tcol * 64 + rr) * 2048 + trow * 64 + c2;
        dst[o]     = v0;
        dst[o + 1] = v1;
    }
}

// ---------- K0b: x fp32 -> bf16 ----------
__global__ __launch_bounds__(256) void cvt_x_kernel(const float* __restrict__ x,
                                                    __bf16* __restrict__ xb)
{
    size_t idx = ((size_t)blockIdx.x * 256 + threadIdx.x) * 4;
    fv4 v = *(const fv4*)(x + idx);
    bv4 o;
#pragma unroll
    for (int u = 0; u < 4; u++) o[u] = (__bf16)v[u];
    *(bv4*)(xb + idx) = o;
}

// ---------- K1: g = gelu(x @ wg1), fp32 (top-k precision-critical) ----------
__global__ __launch_bounds__(256) void gating_gemm(const float* __restrict__ x,
                                                   const float* __restrict__ wg1,
                                                   float* __restrict__ g)
{
    __shared__ float As[16][68];
    __shared__ float Bs[16][68];
    int tid = threadIdx.x;
    int tx = tid & 15, ty = tid >> 4;
    int mb = blockIdx.x, nb = blockIdx.y;
    float acc[4][4];
#pragma unroll
    for (int u = 0; u < 4; u++)
#pragma unroll
        for (int v = 0; v < 4; v++) acc[u][v] = 0.f;

    int r  = tid >> 2, kq = tid & 3;
    int kb = tid >> 4, n4 = (tid & 15) * 4;
    const float* gx = x + (size_t)(mb * 64 + r) * 2048 + kq * 4;
    const float* gw = wg1 + nb * 64 + n4;

    for (int k0 = 0; k0 < 2048; k0 += 16) {
        fv4 av = *(const fv4*)(gx + k0);
        fv4 bv = *(const fv4*)(gw + (size_t)(k0 + kb) * 256);
        __syncthreads();
#pragma unroll
        for (int u = 0; u < 4; u++) As[kq * 4 + u][r] = av[u];
        *(fv4*)&Bs[kb][n4] = bv;
        __syncthreads();
#pragma unroll
        for (int k = 0; k < 16; k++) {
            fv4 a = *(const fv4*)&As[k][ty * 4];
            fv4 b = *(const fv4*)&Bs[k][tx * 4];
#pragma unroll
            for (int u = 0; u < 4; u++)
#pragma unroll
                for (int v = 0; v < 4; v++) acc[u][v] += a[u] * b[v];
        }
    }
#pragma unroll
    for (int u = 0; u < 4; u++) {
        int row = mb * 64 + ty * 4 + u;
#pragma unroll
        for (int v = 0; v < 4; v++)
            g[(size_t)row * 256 + nb * 64 + tx * 4 + v] = gelu_f(acc[u][v]);
    }
}

// ---------- K2: logits = g @ wg2, softmax, top-2, loss partials ----------
__global__ __launch_bounds__(256) void gate_kernel(
    const float* __restrict__ g, const float* __restrict__ wg2,
    Ctrl* __restrict__ ctrl, int* __restrict__ topidx, float* __restrict__ topval)
{
    __shared__ float wg2s[256 * 9];
    __shared__ float psum_s[8];
    __shared__ float ent_s;
    __shared__ int   cnt_s[8];
    int tid = threadIdx.x;
    for (int i = tid; i < 2048; i += 256) {
        int k = i >> 3, e = i & 7;
        wg2s[k * 9 + e] = wg2[i];
    }
    if (tid < 8) { psum_s[tid] = 0.f; cnt_s[tid] = 0; }
    if (tid == 8) ent_s = 0.f;
    __syncthreads();

    int lane = tid & 63, wv = tid >> 6;
    int t = blockIdx.x * 4 + wv;
    fv4 g4 = *(const fv4*)&g[(size_t)t * 256 + lane * 4];
    float part[8];
#pragma unroll
    for (int e = 0; e < 8; e++) part[e] = 0.f;
#pragma unroll
    for (int u = 0; u < 4; u++) {
        int k = lane * 4 + u;
        float gv = g4[u];
#pragma unroll
        for (int e = 0; e < 8; e++) part[e] += gv * wg2s[k * 9 + e];
    }
#pragma unroll
    for (int e = 0; e < 8; e++)
        for (int off = 32; off; off >>= 1) part[e] += __shfl_xor(part[e], off);

    if (lane == 0) {
        float mx = part[0];
#pragma unroll
        for (int e = 1; e < 8; e++) mx = fmaxf(mx, part[e]);
        float p[8], Z = 0.f;
#pragma unroll
        for (int e = 0; e < 8; e++) { p[e] = expf(part[e] - mx); Z += p[e]; }
        float rz = 1.f / Z;
#pragma unroll
        for (int e = 0; e < 8; e++) p[e] *= rz;
        int i0 = 0;
#pragma unroll
        for (int e = 1; e < 8; e++) if (part[e] > part[i0]) i0 = e;
        int i1 = (i0 == 0) ? 1 : 0;
#pragma unroll
        for (int e = 0; e < 8; e++)
            if (e != i0 && part[e] > part[i1]) i1 = e;
        topidx[2 * t]     = i0;
        topidx[2 * t + 1] = i1;
        topval[2 * t]     = p[i0];
        topval[2 * t + 1] = p[i1];
        float ent = 0.f;
#pragma unroll
        for (int e = 0; e < 8; e++) ent += p[e] * logf(p[e] + 1e-9f);
#pragma unroll
        for (int e = 0; e < 8; e++) atomicAdd(&psum_s[e], p[e]);
        atomicAdd(&ent_s, ent);
        atomicAdd(&cnt_s[i0], 1);
        atomicAdd(&cnt_s[i1], 1);
    }
    __syncthreads();
    if (tid < 8)                    atomicAdd(&ctrl->psum[tid], psum_s[tid]);
    else if (tid == 8)              atomicAdd(&ctrl->entsum, ent_s);
    else if (tid >= 16 && tid < 24) atomicAdd(&ctrl->counts[tid - 16], cnt_s[tid - 16]);
}

// ---------- K4: offsets + tile map (128-granular) + scatter ----------
__global__ __launch_bounds__(256) void route_kernel(
    Ctrl* __restrict__ ctrl, const int* __restrict__ topidx,
    const float* __restrict__ topval, int* __restrict__ rowtok,
    float* __restrict__ rowgate)
{
    __shared__ int cur[8];
    __shared__ int offs_s[8];
    int tid = threadIdx.x;
    if (tid == 0) {
        int off = 0, nt = 0;
        for (int e = 0; e < 8; e++) {
            offs_s[e]    = off;
            ctrl->off[e] = off;
            int c = ctrl->counts[e];
            for (int m = 0; m < c; m += 128) {
                ctrl->tile_e[nt]  = e;
                ctrl->tile_r0[nt] = off + m;
                nt++;
            }
            off += ((c + 127) >> 7) << 7;
        }
        ctrl->ntiles = nt;
    }
    if (tid < 8) cur[tid] = 0;
    __syncthreads();
    for (int t = tid; t < T_TOK; t += 256) {
#pragma unroll
        for (int k = 0; k < 2; k++) {
            int e = topidx[2 * t + k];
            int p = atomicAdd(&cur[e], 1);
            int row = offs_s[e] + p;
            rowtok[row]  = t;
            rowgate[row] = topval[2 * t + k];
        }
    }
}

// ---------- grouped MFMA GEMM: m97-proven structure + verified XOR swizzle ----------
// 128x128 tile, BK=32, 4 waves (2x2), single-buffered 16KB LDS, plain
// __syncthreads() double-barrier K-loop. One item per block; 1152 blocks all
// co-resident (~4.5/CU at 16KB LDS / 60 VGPR) hide the barrier vmcnt drain.
// LDS [128][32] bf16: row = 4 chunks of 16B. Both-sides swizzle (rule #21):
//   logical chunk at (row p, phys chunk q) is q ^ ((p>>1)&3)
//   stage: linear g2l16 dest, source k-chunk = (tid&3) ^ ((tid>>3)&3)
//   read:  phys chunk = (lane>>4) ^ ((lane>>1)&3)  -> rows 0..7 cover all 8
//          bank quads, 2 lanes/bank = conflict-free (round-0 kernel: 9216 cnt)
#define NBLK 1152

template <bool IS_FFN1>
__global__ __launch_bounds__(256, 4) void gemm_grouped(
    const __bf16* __restrict__ A,
    const __bf16* __restrict__ Bt,   // [E][N=2048][K=2048] (B^T)
    const Ctrl* __restrict__ ctrl,
    const int* __restrict__ rowtok,
    const float* __restrict__ rowgate,
    __bf16* __restrict__ hbuf,
    float* __restrict__ y)
{
    __shared__ __bf16 As[128 * 32];  // 8 KB
    __shared__ __bf16 Bs[128 * 32];  // 8 KB

    const int tid  = threadIdx.x;
    const int lane = tid & 63, w = tid >> 6;
    const int wm = w >> 1, wn = w & 1;        // 2x2 wave grid, 64x64 per wave
    const int l15 = lane & 15;
    const int kswz8 = (((lane >> 4) ^ ((lane >> 1) & 3)) << 3);  // swizzled k-chunk (elems)
    const int stb = w * 512;                  // wave-uniform LDS dest (elements)
    const int srow = tid >> 2;                // staging dest/source row (0..63)
    const int sk8  = (((tid & 3) ^ ((tid >> 3) & 3)) << 3);      // inv-swizzled src chunk

    int ntiles = ctrl->ntiles;
    int nitems = ntiles << 4;                 // x 16 col panels (nb)
    int item = (blockIdx.x & 7) * (NBLK / 8) + (blockIdx.x >> 3);  // XCD-chunked
    if (item >= nitems) return;

    int tl = item >> 4, nb = item & 15;
    int e  = ctrl->tile_e[tl];
    int r0 = ctrl->tile_r0[tl];

    // staging source pointers (k=0)
    int rA0, rA1;
    if constexpr (IS_FFN1) {
        rA0 = rowtok[r0 + srow];
        rA1 = rowtok[r0 + 64 + srow];
    } else {
        rA0 = r0 + srow;
        rA1 = rA0 + 64;
    }
    const __bf16* pa0 = A + (size_t)rA0 * 2048 + sk8;
    const __bf16* pa1 = A + (size_t)rA1 * 2048 + sk8;
    const __bf16* pb0 = Bt + ((size_t)e * 2048 + nb * 128 + srow) * 2048 + sk8;
    const __bf16* pb1 = pb0 + (size_t)64 * 2048;

    fv4 acc[4][4];
#pragma unroll
    for (int i = 0; i < 4; i++)
#pragma unroll
        for (int j = 0; j < 4; j++) acc[i][j] = (fv4)0.0f;

    for (int k = 0; k < 2048; k += 32) {
        __syncthreads();                    // prior step's reads complete
        g2l16(pa0 + k, As + stb);           // rows 0..63
        g2l16(pa1 + k, As + 2048 + stb);    // rows 64..127
        g2l16(pb0 + k, Bs + stb);
        g2l16(pb1 + k, Bs + 2048 + stb);
        __syncthreads();                    // compiler drains vmcnt before barrier

        bv8 aF[4], bF[4];
#pragma unroll
        for (int i = 0; i < 4; i++)
            aF[i] = *(const bv8*)&As[(wm * 64 + i * 16 + l15) * 32 + kswz8];
#pragma unroll
        for (int j = 0; j < 4; j++)
            bF[j] = *(const bv8*)&Bs[(wn * 64 + j * 16 + l15) * 32 + kswz8];
#pragma unroll
        for (int i = 0; i < 4; i++)
#pragma unroll
            for (int j = 0; j < 4; j++)
                acc[i][j] = __builtin_amdgcn_mfma_f32_16x16x32_bf16(
                    aF[i], bF[j], acc[i][j], 0, 0, 0);
    }

    // epilogue: C/D layout col=lane&15, row=(lane>>4)*4+reg
    int colb = nb * 128 + wn * 64 + l15;
    int rb   = r0 + wm * 64 + (lane >> 4) * 4;
#pragma unroll
    for (int i = 0; i < 4; i++) {
#pragma unroll
        for (int rr = 0; rr < 4; rr++) {
            int rg = rb + i * 16 + rr;
            if constexpr (IS_FFN1) {
                float gate = rowgate[rg];
                size_t ho = (size_t)rg * 2048;
#pragma unroll
                for (int j = 0; j < 4; j++)
                    hbuf[ho + colb + j * 16] = (__bf16)(gelu_f(acc[i][j][rr]) * gate);
            } else {
                size_t yo = (size_t)rowtok[rg] * 2048;
#pragma unroll
                for (int j = 0; j < 4; j++)
                    atomicAdd(&y[yo + colb + j * 16], acc[i][j][rr]);
            }
        }
    }
}

// ---------- K5: final loss scalar ----------
__global__ __launch_bounds__(64) void loss_kernel(const Ctrl* __restrict__ ctrl,
                                                  float* __restrict__ out)
{
    if (threadIdx.x == 0) {
        float a = 0.f;
#pragma unroll
        for (int e = 0; e < 8; e++) {
            float pm = ctrl->psum[e] * (1.0f / 4096.0f);
            a += pm * logf(pm + 1e-9f);
        }
        out[0] = a - ctrl->entsum * (1.0f / 4096.0f);
    }
}

extern "C" void kernel_launch(void* const* d_in, const int* in_sizes, int n_in,
                              void* d_out, int out_size, void* d_ws, size_t ws_size,
                              hipStream_t stream)
{
    const float* x   = (const float*)d_in[0];
    const float* wg1 = (const float*)d_in[1];
    const float* wg2 = (const float*)d_in[2];
    const float* w1  = (const float*)d_in[3];
    const float* w2  = (const float*)d_in[4];
    float* out = (float*)d_out;

    char* ws = (char*)d_ws;
    Ctrl*   ctrl    = (Ctrl*)(ws + CTRL_OFF);
    int*    rowtok  = (int*)(ws + ROWTOK_OFF);
    float*  rowgate = (float*)(ws + ROWGATE_OFF);
    int*    topidx  = (int*)(ws + TOPIDX_OFF);
    float*  topval  = (float*)(ws + TOPVAL_OFF);
    float*  g       = (float*)(ws + G_OFF);
    __bf16* xb      = (__bf16*)(ws + XB_OFF);
    __bf16* w1t     = (__bf16*)(ws + W1T_OFF);
    __bf16* w2t     = (__bf16*)(ws + W2T_OFF);
    __bf16* hbuf    = (__bf16*)(ws + HBUF_OFF);

    hipMemsetAsync(ws + CTRL_OFF, 0, 4096, stream);
    hipMemsetAsync(ws + ROWTOK_OFF, 0, 81920, stream);   // rowtok + rowgate
    hipMemsetAsync(d_out, 0, (size_t)out_size * sizeof(float), stream);

    transpose_cvt<<<16384, 256, 0, stream>>>(w1, w2, w1t, w2t);
    cvt_x_kernel<<<8192, 256, 0, stream>>>(x, xb);
    gating_gemm<<<dim3(64, 4), 256, 0, stream>>>(x, wg1, g);
    gate_kernel<<<1024, 256, 0, stream>>>(g, wg2, ctrl, topidx, topval);
    route_kernel<<<1, 256, 0, stream>>>(ctrl, topidx, topval, rowtok, rowgate);
    gemm_grouped<true><<<NBLK, 256, 0, stream>>>(xb, w1t, ctrl, rowtok, rowgate, hbuf, nullptr);
    gemm_grouped<false><<<NBLK, 256, 0, stream>>>(hbuf, w2t, ctrl, rowtok, rowgate, nullptr, out);
    loss_kernel<<<1, 64, 0, stream>>>(ctrl, out + 8388608);
}